// Round 17
// baseline (2020.168 us; speedup 1.0000x reference)
//
#include <hip/hip_runtime.h>
#include <hip/hip_bf16.h>
#include <cstdint>
#include <cstddef>

#define N_TOK 65536
#define HIDDEN 768
#define NHEAD 12
#define HEADD 64

typedef __bf16 bf16x8 __attribute__((ext_vector_type(8)));
typedef float f32x4 __attribute__((ext_vector_type(4)));

__device__ __forceinline__ float bflo(unsigned int u) {
  return __builtin_bit_cast(float, (unsigned int)(u << 16));
}
__device__ __forceinline__ float bfhi(unsigned int u) {
  return __builtin_bit_cast(float, (unsigned int)(u & 0xffff0000u));
}
__device__ __forceinline__ unsigned short f2bf(float f) {
  unsigned int x = __builtin_bit_cast(unsigned int, f);
  unsigned int r = x + 0x7fffu + ((x >> 16) & 1u);  // RTNE
  return (unsigned short)(r >> 16);
}
__device__ __forceinline__ unsigned int pk2bf(float a, float b) {
  return (unsigned int)f2bf(a) | ((unsigned int)f2bf(b) << 16);
}

__device__ __forceinline__ void gload_lds16(const void* g, void* l) {
  __builtin_amdgcn_global_load_lds(
      (const __attribute__((address_space(1))) void*)g,
      (__attribute__((address_space(3))) void*)l, 16, 0, 0);
}

// GEMM LDS swizzle: physical = logical ^ ((row&7)<<4). (verified: 0 conflicts)
__device__ __forceinline__ bf16x8 ldsfrag(const char* base, int row, int kb) {
  int L = (row << 7) + kb;
  L ^= (row & 7) << 4;
  return *(const bf16x8*)(base + L);
}

// attn LDS within-row swizzle
__device__ __forceinline__ int swz(int loff) {
  return loff ^ (((loff >> 7) & 7) << 4);
}

// ------- weight converts + bias concat (x-convert fused into GEMM1) -----
__global__ void cvtw_kernel(const float* __restrict__ Wq, const float* __restrict__ Wk,
                            const float* __restrict__ Wv, const float* __restrict__ Wo,
                            const float* __restrict__ bq, const float* __restrict__ bk,
                            const float* __restrict__ bv,
                            unsigned short* __restrict__ wqkv,
                            unsigned short* __restrict__ wo_bf,
                            float* __restrict__ bqkv) {
  const int bid = blockIdx.x;
  if (bid < 2304) {
    const int mat = bid / 576;
    const int idx = (bid - mat * 576) * 256 + threadIdx.x;
    const float* src = mat == 0 ? Wq : mat == 1 ? Wk : mat == 2 ? Wv : Wo;
    unsigned short* dst = (mat == 3) ? wo_bf : wqkv + mat * (HIDDEN * HIDDEN);
    float4 v = ((const float4*)src)[idx];
    ushort4 o;
    o.x = f2bf(v.x); o.y = f2bf(v.y); o.z = f2bf(v.z); o.w = f2bf(v.w);
    ((ushort4*)dst)[idx] = o;
  } else {
    const int i = (bid - 2304) * 256 + threadIdx.x;
    if (i < 576) {
      const float* src = i < 192 ? bq : i < 384 ? bk : bv;
      const int off = i < 192 ? i : i < 384 ? i - 192 : i - 384;
      ((float4*)bqkv)[i] = ((const float4*)src)[off];
    }
  }
}

// ------------- 256x256 bf16 GEMM, 1024 thr = 16 waves (4M x 4N) --------------
// MODE 0: bf16 A, bf16 out.  MODE 1: bf16 A, f32 out (R15 proven schedule).
// MODE 2: f32 A (in-staging convert), bf16 out. R17: __launch_bounds__(1024,4)
// raises the VGPR cap to 128 so the a4[] staging registers don't spill
// (R16: default 64-VGPR target -> 4.8 GB scratch traffic, 7x slowdown).
template <int MODE>
__global__ __launch_bounds__(1024, 4)
void gemm256(const void* __restrict__ Av, const unsigned short* __restrict__ B,
             const float* __restrict__ bias,
             void* __restrict__ C, int K, int NBLK, int ldc) {
  const unsigned short* A = (const unsigned short*)Av;
  const float* Af = (const float*)Av;
  __shared__ __align__(16) char lds[131072];
  const int tid = threadIdx.x;
  const int lane = tid & 63;
  const int wave = tid >> 6;
  const int wr = wave >> 2;
  const int wc = wave & 3;

  const int nwg = gridDim.x;
  const int bid = blockIdx.x;
  const int wg = (bid & 7) * (nwg >> 3) + (bid >> 3);
  const int mb = wg / NBLK;
  const int nb = wg - mb * NBLK;
  const int brow = mb << 8;
  const int bcol = nb << 8;

  const int Ld = tid * 16;
  const int Ls = Ld ^ (((tid >> 3) & 7) << 4);
  const int sr = Ls >> 7;
  const int sc = (Ls & 127) >> 1;

  const int NT = K >> 6;

#define STAGE(Mat, panelRow, bufbase, matoff, half, kt)                         \
  do {                                                                          \
    const unsigned short* _s =                                                  \
        (Mat) + (size_t)((panelRow) + (half) * 128 + sr) * K + ((kt) << 6) + sc;\
    char* _d = (char*)lds + (bufbase) + (matoff) + ((half) << 14) + Ld;         \
    gload_lds16(_s, _d);                                                        \
  } while (0)

  f32x4 acc[4][4];
#pragma unroll
  for (int m = 0; m < 4; ++m)
#pragma unroll
    for (int n = 0; n < 4; ++n) acc[m][n] = (f32x4){0.f, 0.f, 0.f, 0.f};

  const int arow = wr * 64 + (lane & 15);
  const int nrow = wc * 64 + (lane & 15);
  const int kpart = (lane >> 4) * 16;

  // ---- prologue ----
  if (MODE == 2) {
    const float* s0 = Af + (size_t)(brow + sr) * K + sc;
    const float* s1 = s0 + (size_t)128 * K;
    float4 p0 = ((const float4*)s0)[0], p1 = ((const float4*)s0)[1];
    float4 p2 = ((const float4*)s1)[0], p3 = ((const float4*)s1)[1];
    STAGE(B, bcol, 0, 32768, 0, 0);
    STAGE(B, bcol, 0, 32768, 1, 0);
    uint4 w0, w1;
    w0.x = pk2bf(p0.x, p0.y); w0.y = pk2bf(p0.z, p0.w);
    w0.z = pk2bf(p1.x, p1.y); w0.w = pk2bf(p1.z, p1.w);
    w1.x = pk2bf(p2.x, p2.y); w1.y = pk2bf(p2.z, p2.w);
    w1.z = pk2bf(p3.x, p3.y); w1.w = pk2bf(p3.z, p3.w);
    *(uint4*)(lds + Ld) = w0;
    *(uint4*)(lds + 16384 + Ld) = w1;
    asm volatile("s_waitcnt vmcnt(0) lgkmcnt(0)" ::: "memory");
  } else {
    STAGE(A, brow, 0, 0, 0, 0);
    STAGE(A, brow, 0, 0, 1, 0);
    STAGE(B, bcol, 0, 32768, 0, 0);
    STAGE(B, bcol, 0, 32768, 1, 0);
    if (NT > 1) {
      STAGE(A, brow, 65536, 0, 0, 1);
      STAGE(A, brow, 65536, 0, 1, 1);
      asm volatile("s_waitcnt vmcnt(2)" ::: "memory");
    } else {
      asm volatile("s_waitcnt vmcnt(0)" ::: "memory");
    }
  }
  __builtin_amdgcn_s_barrier();

  for (int t = 0; t < NT; ++t) {
    const int cur = t & 1;
    const char* la = lds + cur * 65536;
    const char* lb = la + 32768;
    const int sbuf = cur * 65536;
    const int obuf = (cur ^ 1) * 65536;

    bf16x8 aF[4], bLo[2], bHi[2];
    float4 a4[4];  // MODE==2 only: A(t+1) f32 staged in regs

    // ---- PH1: read A-kk0+B-kk0-lo; stage B(t+1); [MODE2: issue A(t+1) f32] --
#pragma unroll
    for (int m = 0; m < 4; ++m) aF[m] = ldsfrag(la, arow + m * 16, kpart);
#pragma unroll
    for (int n = 0; n < 2; ++n) bLo[n] = ldsfrag(lb, nrow + n * 16, kpart);
    if (t + 1 < NT) {
      STAGE(B, bcol, obuf, 32768, 0, t + 1);
      STAGE(B, bcol, obuf, 32768, 1, t + 1);
      if (MODE == 2) {
        const float* s0 = Af + (size_t)(brow + sr) * K + (t + 1) * 64 + sc;
        const float* s1 = s0 + (size_t)128 * K;
        a4[0] = ((const float4*)s0)[0];
        a4[1] = ((const float4*)s0)[1];
        a4[2] = ((const float4*)s1)[0];
        a4[3] = ((const float4*)s1)[1];
      }
    }
    __builtin_amdgcn_s_barrier();
    asm volatile("s_waitcnt lgkmcnt(0)" ::: "memory");
    __builtin_amdgcn_sched_barrier(0);
    __builtin_amdgcn_s_setprio(1);
#pragma unroll
    for (int m = 0; m < 4; ++m)
#pragma unroll
      for (int n = 0; n < 2; ++n)
        acc[m][n] = __builtin_amdgcn_mfma_f32_16x16x32_bf16(aF[m], bLo[n],
                                                            acc[m][n], 0, 0, 0);
    __builtin_amdgcn_s_setprio(0);

    // ---- PH2: read B-kk0-hi; MFMA kk0 x nhi ----
#pragma unroll
    for (int n = 0; n < 2; ++n) bHi[n] = ldsfrag(lb, nrow + 32 + n * 16, kpart);
    __builtin_amdgcn_s_barrier();
    asm volatile("s_waitcnt lgkmcnt(0)" ::: "memory");
    __builtin_amdgcn_sched_barrier(0);
    __builtin_amdgcn_s_setprio(1);
#pragma unroll
    for (int m = 0; m < 4; ++m)
#pragma unroll
      for (int n = 0; n < 2; ++n)
        acc[m][n + 2] = __builtin_amdgcn_mfma_f32_16x16x32_bf16(
            aF[m], bHi[n], acc[m][n + 2], 0, 0, 0);
    __builtin_amdgcn_s_setprio(0);

    // ---- PH3: read A-kk1+B-kk1-lo; MFMA kk1 x nlo ----
#pragma unroll
    for (int m = 0; m < 4; ++m) aF[m] = ldsfrag(la, arow + m * 16, 64 + kpart);
#pragma unroll
    for (int n = 0; n < 2; ++n) bLo[n] = ldsfrag(lb, nrow + n * 16, 64 + kpart);
    __builtin_amdgcn_s_barrier();
    asm volatile("s_waitcnt lgkmcnt(0)" ::: "memory");
    __builtin_amdgcn_sched_barrier(0);
    __builtin_amdgcn_s_setprio(1);
#pragma unroll
    for (int m = 0; m < 4; ++m)
#pragma unroll
      for (int n = 0; n < 2; ++n)
        acc[m][n] = __builtin_amdgcn_mfma_f32_16x16x32_bf16(aF[m], bLo[n],
                                                            acc[m][n], 0, 0, 0);
    __builtin_amdgcn_s_setprio(0);

    // ---- PH4: read B-kk1-hi; A-stage finalize; MFMA kk1 x nhi ----
#pragma unroll
    for (int n = 0; n < 2; ++n)
      bHi[n] = ldsfrag(lb, nrow + 32 + n * 16, 64 + kpart);
    if (MODE == 2) {
      if (t + 1 < NT) {
        asm volatile("s_waitcnt vmcnt(0)" ::: "memory");  // 3-phase-old loads
        uint4 w0, w1;
        w0.x = pk2bf(a4[0].x, a4[0].y); w0.y = pk2bf(a4[0].z, a4[0].w);
        w0.z = pk2bf(a4[1].x, a4[1].y); w0.w = pk2bf(a4[1].z, a4[1].w);
        w1.x = pk2bf(a4[2].x, a4[2].y); w1.y = pk2bf(a4[2].z, a4[2].w);
        w1.z = pk2bf(a4[3].x, a4[3].y); w1.w = pk2bf(a4[3].z, a4[3].w);
        *(uint4*)(lds + obuf + Ld) = w0;
        *(uint4*)(lds + obuf + 16384 + Ld) = w1;
      }
      asm volatile("s_waitcnt lgkmcnt(0)" ::: "memory");  // writes visible pre-barrier
      __builtin_amdgcn_s_barrier();
      __builtin_amdgcn_sched_barrier(0);
    } else {
      if (t + 2 < NT) {
        STAGE(A, brow, sbuf, 0, 0, t + 2);
        STAGE(A, brow, sbuf, 0, 1, t + 2);
        asm volatile("s_waitcnt vmcnt(2)" ::: "memory");
      } else {
        asm volatile("s_waitcnt vmcnt(0)" ::: "memory");
      }
      __builtin_amdgcn_s_barrier();
      asm volatile("s_waitcnt lgkmcnt(0)" ::: "memory");
      __builtin_amdgcn_sched_barrier(0);
    }
    __builtin_amdgcn_s_setprio(1);
#pragma unroll
    for (int m = 0; m < 4; ++m)
#pragma unroll
      for (int n = 0; n < 2; ++n)
        acc[m][n + 2] = __builtin_amdgcn_mfma_f32_16x16x32_bf16(
            aF[m], bHi[n], acc[m][n + 2], 0, 0, 0);
    __builtin_amdgcn_s_setprio(0);
  }
#undef STAGE

  const int crow0 = brow + wr * 64 + (lane >> 4) * 4;
  const int ccol0 = bcol + wc * 64 + (lane & 15);
#pragma unroll
  for (int m = 0; m < 4; ++m) {
#pragma unroll
    for (int n = 0; n < 4; ++n) {
      const int col = ccol0 + n * 16;
      const float bv = bias[col];
#pragma unroll
      for (int r = 0; r < 4; ++r) {
        const int row = crow0 + m * 16 + r;
        const float v = acc[m][n][r] + bv;
        if (MODE == 1)
          ((float*)C)[(size_t)row * ldc + col] = v;
        else
          ((unsigned short*)C)[(size_t)row * ldc + col] = f2bf(v);
      }
    }
  }
}

// ---------------- LDS-staged per-token 12x12 attention (R14, working) --------
#define T_BLK 8
#define ROWB 4624

__global__ __launch_bounds__(128)
void attn_kernel(const unsigned short* __restrict__ qkv,
                 unsigned short* __restrict__ ctx) {
  __shared__ __align__(16) char lds[T_BLK * ROWB];
  const int tid = threadIdx.x;
  const int blk = blockIdx.x;

  const uint4* src = (const uint4*)(qkv + (size_t)blk * (T_BLK * 2304));
#pragma unroll
  for (int it = 0; it < 18; ++it) {
    const int l = it * 128 + tid;
    const uint4 v = src[l];
    const int tok = l / 288;
    const int loff = (l - tok * 288) * 16;
    *(uint4*)(lds + tok * ROWB + swz(loff)) = v;
  }
  __syncthreads();

  const int tok = tid / 12;
  const int h = tid - tok * 12;
  const bool active = (tid < 96);
  const char* rowb = lds + tok * ROWB;

  float p[12];
  if (active) {
    float s[12];
#pragma unroll
    for (int g = 0; g < 12; ++g) s[g] = 0.f;
#pragma unroll
    for (int c = 0; c < 8; ++c) {
      const uint4 qc = *(const uint4*)(rowb + swz(h * 128 + c * 16));
      const unsigned int qw[4] = {qc.x, qc.y, qc.z, qc.w};
      float qd[8];
#pragma unroll
      for (int w = 0; w < 4; ++w) {
        qd[2 * w] = bflo(qw[w]);
        qd[2 * w + 1] = bfhi(qw[w]);
      }
#pragma unroll
      for (int j = 0; j < 8; ++j) {
        const int koff = 1536 + (c * 8 + j) * 24;
        const uint2 k0 = *(const uint2*)(rowb + swz(koff));
        const uint2 k1 = *(const uint2*)(rowb + swz(koff + 8));
        const uint2 k2 = *(const uint2*)(rowb + swz(koff + 16));
        const float q = qd[j];
        s[0] += q * bflo(k0.x);  s[1] += q * bfhi(k0.x);
        s[2] += q * bflo(k0.y);  s[3] += q * bfhi(k0.y);
        s[4] += q * bflo(k1.x);  s[5] += q * bfhi(k1.x);
        s[6] += q * bflo(k1.y);  s[7] += q * bfhi(k1.y);
        s[8] += q * bflo(k2.x);  s[9] += q * bfhi(k2.x);
        s[10] += q * bflo(k2.y); s[11] += q * bfhi(k2.y);
      }
    }
    float mx = s[0];
#pragma unroll
    for (int g = 1; g < 12; ++g) mx = fmaxf(mx, s[g]);
    float sum = 0.f;
#pragma unroll
    for (int g = 0; g < 12; ++g) {
      p[g] = __expf((s[g] - mx) * 0.125f);
      sum += p[g];
    }
    const float inv = 1.0f / sum;
#pragma unroll
    for (int g = 0; g < 12; ++g) p[g] *= inv;
  }

  __syncthreads();

  if (active) {
    char* qpark = lds + tok * ROWB;
#pragma unroll
    for (int c = 0; c < 8; ++c) {
      float o[8];
#pragma unroll
      for (int k = 0; k < 8; ++k) o[k] = 0.f;
#pragma unroll
      for (int g = 0; g < 12; ++g) {
        const uint4 vv = *(const uint4*)(rowb + swz(3072 + g * 128 + c * 16));
        const unsigned int vw[4] = {vv.x, vv.y, vv.z, vv.w};
#pragma unroll
        for (int k = 0; k < 4; ++k) {
          o[2 * k] += p[g] * bflo(vw[k]);
          o[2 * k + 1] += p[g] * bfhi(vw[k]);
        }
      }
      uint4 w;
      w.x = (unsigned int)f2bf(o[0]) | ((unsigned int)f2bf(o[1]) << 16);
      w.y = (unsigned int)f2bf(o[2]) | ((unsigned int)f2bf(o[3]) << 16);
      w.z = (unsigned int)f2bf(o[4]) | ((unsigned int)f2bf(o[5]) << 16);
      w.w = (unsigned int)f2bf(o[6]) | ((unsigned int)f2bf(o[7]) << 16);
      *(uint4*)(qpark + swz(h * 128 + c * 16)) = w;
    }
  }
  __syncthreads();

  uint4* dst = (uint4*)(ctx + (size_t)blk * (T_BLK * 768));
#pragma unroll
  for (int it = 0; it < 6; ++it) {
    const int l = it * 128 + tid;
    const int tok2 = l / 96;
    const int boff = (l - tok2 * 96) * 16;
    dst[l] = *(const uint4*)(lds + tok2 * ROWB + swz(boff));
  }
}

extern "C" void kernel_launch(void* const* d_in, const int* in_sizes, int n_in,
                              void* d_out, int out_size, void* d_ws, size_t ws_size,
                              hipStream_t stream) {
  const float* x = (const float*)d_in[0];
  const float* Wq = (const float*)d_in[1];
  const float* bq = (const float*)d_in[2];
  const float* Wk = (const float*)d_in[3];
  const float* bk = (const float*)d_in[4];
  const float* Wv = (const float*)d_in[5];
  const float* bv = (const float*)d_in[6];
  const float* Wo = (const float*)d_in[7];
  const float* bo = (const float*)d_in[8];
  float* out = (float*)d_out;

  char* ws = (char*)d_ws;
  unsigned short* ctx = (unsigned short*)ws;
  unsigned short* qkv = (unsigned short*)(ws + 100663296u);
  unsigned short* wqkv = (unsigned short*)(ws + 402653184u);
  unsigned short* wo_bf = (unsigned short*)(ws + 406192128u);
  float* bqkv = (float*)(ws + 407371776u);

  // weight converts + bias concat only (x-convert fused into GEMM1)
  cvtw_kernel<<<2307, 256, 0, stream>>>(Wq, Wk, Wv, Wo, bq, bk, bv,
                                        wqkv, wo_bf, bqkv);

  // QKV GEMM, f32 A with in-staging convert
  gemm256<2><<<(N_TOK / 256) * (2304 / 256), 1024, 0, stream>>>(
      x, wqkv, bqkv, qkv, HIDDEN, 2304 / 256, 2304);

  attn_kernel<<<N_TOK / T_BLK, 128, 0, stream>>>(qkv, ctx);

  gemm256<1><<<(N_TOK / 256) * (HIDDEN / 256), 1024, 0, stream>>>(
      ctx, wo_bf, bo, out, HIDDEN, HIDDEN / 256, HIDDEN);
}

// Round 18
// 505.121 us; speedup vs baseline: 3.9994x; 3.9994x over previous
//
#include <hip/hip_runtime.h>
#include <hip/hip_bf16.h>
#include <cstdint>
#include <cstddef>

#define N_TOK 65536
#define HIDDEN 768
#define NHEAD 12
#define HEADD 64

typedef __bf16 bf16x8 __attribute__((ext_vector_type(8)));
typedef float f32x4 __attribute__((ext_vector_type(4)));

__device__ __forceinline__ float bflo(unsigned int u) {
  return __builtin_bit_cast(float, (unsigned int)(u << 16));
}
__device__ __forceinline__ float bfhi(unsigned int u) {
  return __builtin_bit_cast(float, (unsigned int)(u & 0xffff0000u));
}
__device__ __forceinline__ unsigned short f2bf(float f) {
  unsigned int x = __builtin_bit_cast(unsigned int, f);
  unsigned int r = x + 0x7fffu + ((x >> 16) & 1u);  // RTNE
  return (unsigned short)(r >> 16);
}

__device__ __forceinline__ void gload_lds16(const void* g, void* l) {
  __builtin_amdgcn_global_load_lds(
      (const __attribute__((address_space(1))) void*)g,
      (__attribute__((address_space(3))) void*)l, 16, 0, 0);
}

// GEMM LDS swizzle: physical = logical ^ ((row&7)<<4). (verified: 0 conflicts)
__device__ __forceinline__ bf16x8 ldsfrag(const char* base, int row, int kb) {
  int L = (row << 7) + kb;
  L ^= (row & 7) << 4;
  return *(const bf16x8*)(base + L);
}

// attn LDS within-row swizzle
__device__ __forceinline__ int swz(int loff) {
  return loff ^ (((loff >> 7) & 7) << 4);
}

// ------- ALL converts in one launch: x, 4 weights, bias concat -------
__global__ void cvt_all_kernel(const float* __restrict__ x,
                               const float* __restrict__ Wq, const float* __restrict__ Wk,
                               const float* __restrict__ Wv, const float* __restrict__ Wo,
                               const float* __restrict__ bq, const float* __restrict__ bk,
                               const float* __restrict__ bv,
                               unsigned short* __restrict__ x_bf,
                               unsigned short* __restrict__ wqkv,
                               unsigned short* __restrict__ wo_bf,
                               float* __restrict__ bqkv) {
  const int bid = blockIdx.x;
  if (bid < 49152) {
    const int idx = bid * 256 + threadIdx.x;
    float4 v = ((const float4*)x)[idx];
    ushort4 o;
    o.x = f2bf(v.x); o.y = f2bf(v.y); o.z = f2bf(v.z); o.w = f2bf(v.w);
    ((ushort4*)x_bf)[idx] = o;
  } else if (bid < 51456) {
    const int wb = bid - 49152;
    const int mat = wb / 576;
    const int idx = (wb - mat * 576) * 256 + threadIdx.x;
    const float* src = mat == 0 ? Wq : mat == 1 ? Wk : mat == 2 ? Wv : Wo;
    unsigned short* dst = (mat == 3) ? wo_bf : wqkv + mat * (HIDDEN * HIDDEN);
    float4 v = ((const float4*)src)[idx];
    ushort4 o;
    o.x = f2bf(v.x); o.y = f2bf(v.y); o.z = f2bf(v.z); o.w = f2bf(v.w);
    ((ushort4*)dst)[idx] = o;
  } else {
    const int i = (bid - 51456) * 256 + threadIdx.x;
    if (i < 576) {
      const float* src = i < 192 ? bq : i < 384 ? bk : bv;
      const int off = i < 192 ? i : i < 384 ? i - 192 : i - 384;
      ((float4*)bqkv)[i] = ((const float4*)src)[off];
    }
  }
}

// ------------- 256x256 bf16 GEMM, 1024 thr = 16 waves (4M x 4N) --------------
// R15 config: counted-vmcnt 2-tile prefetch. B(t+1) staged PH1(t), A(t+2)
// staged PH4(t), boundary vmcnt(2) -- never drains to 0 in the main loop.
template <int MODE>  // 0: bf16 out, 1: f32 out
__global__ __launch_bounds__(1024)
void gemm256(const unsigned short* __restrict__ A,
             const unsigned short* __restrict__ B,
             const float* __restrict__ bias,
             void* __restrict__ C, int K, int NBLK, int ldc) {
  __shared__ __align__(16) char lds[131072];
  const int tid = threadIdx.x;
  const int lane = tid & 63;
  const int wave = tid >> 6;
  const int wr = wave >> 2;
  const int wc = wave & 3;

  const int nwg = gridDim.x;
  const int bid = blockIdx.x;
  const int wg = (bid & 7) * (nwg >> 3) + (bid >> 3);
  const int mb = wg / NBLK;
  const int nb = wg - mb * NBLK;
  const int brow = mb << 8;
  const int bcol = nb << 8;

  const int Ld = tid * 16;
  const int Ls = Ld ^ (((tid >> 3) & 7) << 4);
  const int sr = Ls >> 7;
  const int sc = (Ls & 127) >> 1;

  const int NT = K >> 6;

#define STAGE(Mat, panelRow, bufbase, matoff, half, kt)                         \
  do {                                                                          \
    const unsigned short* _s =                                                  \
        (Mat) + (size_t)((panelRow) + (half) * 128 + sr) * K + ((kt) << 6) + sc;\
    char* _d = (char*)lds + (bufbase) + (matoff) + ((half) << 14) + Ld;         \
    gload_lds16(_s, _d);                                                        \
  } while (0)

  f32x4 acc[4][4];
#pragma unroll
  for (int m = 0; m < 4; ++m)
#pragma unroll
    for (int n = 0; n < 4; ++n) acc[m][n] = (f32x4){0.f, 0.f, 0.f, 0.f};

  const int arow = wr * 64 + (lane & 15);
  const int nrow = wc * 64 + (lane & 15);
  const int kpart = (lane >> 4) * 16;

  // ---- prologue: stage A(0), B(0), A(1); keep A(1) in flight ----
  STAGE(A, brow, 0, 0, 0, 0);
  STAGE(A, brow, 0, 0, 1, 0);
  STAGE(B, bcol, 0, 32768, 0, 0);
  STAGE(B, bcol, 0, 32768, 1, 0);
  if (NT > 1) {
    STAGE(A, brow, 65536, 0, 0, 1);
    STAGE(A, brow, 65536, 0, 1, 1);
    asm volatile("s_waitcnt vmcnt(2)" ::: "memory");
  } else {
    asm volatile("s_waitcnt vmcnt(0)" ::: "memory");
  }
  __builtin_amdgcn_s_barrier();

  for (int t = 0; t < NT; ++t) {
    const int cur = t & 1;
    const char* la = lds + cur * 65536;
    const char* lb = la + 32768;
    const int sbuf = cur * 65536;        // current buffer; tile t+2 lands here
    const int obuf = (cur ^ 1) * 65536;  // other buffer; tile t+1 lives here

    bf16x8 aF[4], bLo[2], bHi[2];

    // ---- PH1: read A-kk0(4)+B-kk0-lo(2); stage B(t+1) h0+h1; MFMA ----
#pragma unroll
    for (int m = 0; m < 4; ++m) aF[m] = ldsfrag(la, arow + m * 16, kpart);
#pragma unroll
    for (int n = 0; n < 2; ++n) bLo[n] = ldsfrag(lb, nrow + n * 16, kpart);
    if (t + 1 < NT) {
      STAGE(B, bcol, obuf, 32768, 0, t + 1);
      STAGE(B, bcol, obuf, 32768, 1, t + 1);
    }
    __builtin_amdgcn_s_barrier();
    asm volatile("s_waitcnt lgkmcnt(0)" ::: "memory");
    __builtin_amdgcn_sched_barrier(0);
    __builtin_amdgcn_s_setprio(1);
#pragma unroll
    for (int m = 0; m < 4; ++m)
#pragma unroll
      for (int n = 0; n < 2; ++n)
        acc[m][n] = __builtin_amdgcn_mfma_f32_16x16x32_bf16(aF[m], bLo[n],
                                                            acc[m][n], 0, 0, 0);
    __builtin_amdgcn_s_setprio(0);

    // ---- PH2: read B-kk0-hi(2); MFMA kk0 x nhi ----
#pragma unroll
    for (int n = 0; n < 2; ++n) bHi[n] = ldsfrag(lb, nrow + 32 + n * 16, kpart);
    __builtin_amdgcn_s_barrier();
    asm volatile("s_waitcnt lgkmcnt(0)" ::: "memory");
    __builtin_amdgcn_sched_barrier(0);
    __builtin_amdgcn_s_setprio(1);
#pragma unroll
    for (int m = 0; m < 4; ++m)
#pragma unroll
      for (int n = 0; n < 2; ++n)
        acc[m][n + 2] = __builtin_amdgcn_mfma_f32_16x16x32_bf16(
            aF[m], bHi[n], acc[m][n + 2], 0, 0, 0);
    __builtin_amdgcn_s_setprio(0);

    // ---- PH3: read A-kk1(4)+B-kk1-lo(2); MFMA kk1 x nlo ----
#pragma unroll
    for (int m = 0; m < 4; ++m) aF[m] = ldsfrag(la, arow + m * 16, 64 + kpart);
#pragma unroll
    for (int n = 0; n < 2; ++n) bLo[n] = ldsfrag(lb, nrow + n * 16, 64 + kpart);
    __builtin_amdgcn_s_barrier();
    asm volatile("s_waitcnt lgkmcnt(0)" ::: "memory");
    __builtin_amdgcn_sched_barrier(0);
    __builtin_amdgcn_s_setprio(1);
#pragma unroll
    for (int m = 0; m < 4; ++m)
#pragma unroll
      for (int n = 0; n < 2; ++n)
        acc[m][n] = __builtin_amdgcn_mfma_f32_16x16x32_bf16(aF[m], bLo[n],
                                                            acc[m][n], 0, 0, 0);
    __builtin_amdgcn_s_setprio(0);

    // ---- PH4: read B-kk1-hi(2); stage A(t+2); counted vmcnt(2) ----
#pragma unroll
    for (int n = 0; n < 2; ++n)
      bHi[n] = ldsfrag(lb, nrow + 32 + n * 16, 64 + kpart);
    if (t + 2 < NT) {
      STAGE(A, brow, sbuf, 0, 0, t + 2);
      STAGE(A, brow, sbuf, 0, 1, t + 2);
      asm volatile("s_waitcnt vmcnt(2)" ::: "memory");
    } else {
      asm volatile("s_waitcnt vmcnt(0)" ::: "memory");
    }
    __builtin_amdgcn_s_barrier();
    asm volatile("s_waitcnt lgkmcnt(0)" ::: "memory");
    __builtin_amdgcn_sched_barrier(0);
    __builtin_amdgcn_s_setprio(1);
#pragma unroll
    for (int m = 0; m < 4; ++m)
#pragma unroll
      for (int n = 0; n < 2; ++n)
        acc[m][n + 2] = __builtin_amdgcn_mfma_f32_16x16x32_bf16(
            aF[m], bHi[n], acc[m][n + 2], 0, 0, 0);
    __builtin_amdgcn_s_setprio(0);
  }
#undef STAGE

  const int crow0 = brow + wr * 64 + (lane >> 4) * 4;
  const int ccol0 = bcol + wc * 64 + (lane & 15);
#pragma unroll
  for (int m = 0; m < 4; ++m) {
#pragma unroll
    for (int n = 0; n < 4; ++n) {
      const int col = ccol0 + n * 16;
      const float bv = bias[col];
#pragma unroll
      for (int r = 0; r < 4; ++r) {
        const int row = crow0 + m * 16 + r;
        const float v = acc[m][n][r] + bv;
        if (MODE == 1)
          ((float*)C)[(size_t)row * ldc + col] = v;
        else
          ((unsigned short*)C)[(size_t)row * ldc + col] = f2bf(v);
      }
    }
  }
}

// ---------------- LDS-staged per-token 12x12 attention (R14, working) --------
#define T_BLK 8
#define ROWB 4624

__global__ __launch_bounds__(128)
void attn_kernel(const unsigned short* __restrict__ qkv,
                 unsigned short* __restrict__ ctx) {
  __shared__ __align__(16) char lds[T_BLK * ROWB];  // 36992 B
  const int tid = threadIdx.x;
  const int blk = blockIdx.x;

  // ---- stage: 2304 uint4, 18 iters x 128 thr, fully coalesced ----
  const uint4* src = (const uint4*)(qkv + (size_t)blk * (T_BLK * 2304));
#pragma unroll
  for (int it = 0; it < 18; ++it) {
    const int l = it * 128 + tid;
    const uint4 v = src[l];
    const int tok = l / 288;
    const int loff = (l - tok * 288) * 16;
    *(uint4*)(lds + tok * ROWB + swz(loff)) = v;
  }
  __syncthreads();

  const int tok = tid / 12;
  const int h = tid - tok * 12;
  const bool active = (tid < 96);
  const char* rowb = lds + tok * ROWB;

  float p[12];
  if (active) {
    float s[12];
#pragma unroll
    for (int g = 0; g < 12; ++g) s[g] = 0.f;
#pragma unroll
    for (int c = 0; c < 8; ++c) {
      const uint4 qc = *(const uint4*)(rowb + swz(h * 128 + c * 16));
      const unsigned int qw[4] = {qc.x, qc.y, qc.z, qc.w};
      float qd[8];
#pragma unroll
      for (int w = 0; w < 4; ++w) {
        qd[2 * w] = bflo(qw[w]);
        qd[2 * w + 1] = bfhi(qw[w]);
      }
#pragma unroll
      for (int j = 0; j < 8; ++j) {
        const int koff = 1536 + (c * 8 + j) * 24;
        const uint2 k0 = *(const uint2*)(rowb + swz(koff));
        const uint2 k1 = *(const uint2*)(rowb + swz(koff + 8));
        const uint2 k2 = *(const uint2*)(rowb + swz(koff + 16));
        const float q = qd[j];
        s[0] += q * bflo(k0.x);  s[1] += q * bfhi(k0.x);
        s[2] += q * bflo(k0.y);  s[3] += q * bfhi(k0.y);
        s[4] += q * bflo(k1.x);  s[5] += q * bfhi(k1.x);
        s[6] += q * bflo(k1.y);  s[7] += q * bfhi(k1.y);
        s[8] += q * bflo(k2.x);  s[9] += q * bfhi(k2.x);
        s[10] += q * bflo(k2.y); s[11] += q * bfhi(k2.y);
      }
    }
    float mx = s[0];
#pragma unroll
    for (int g = 1; g < 12; ++g) mx = fmaxf(mx, s[g]);
    float sum = 0.f;
#pragma unroll
    for (int g = 0; g < 12; ++g) {
      p[g] = __expf((s[g] - mx) * 0.125f);
      sum += p[g];
    }
    const float inv = 1.0f / sum;
#pragma unroll
    for (int g = 0; g < 12; ++g) p[g] *= inv;
  }

  __syncthreads();

  if (active) {
    char* qpark = lds + tok * ROWB;
#pragma unroll
    for (int c = 0; c < 8; ++c) {
      float o[8];
#pragma unroll
      for (int k = 0; k < 8; ++k) o[k] = 0.f;
#pragma unroll
      for (int g = 0; g < 12; ++g) {
        const uint4 vv = *(const uint4*)(rowb + swz(3072 + g * 128 + c * 16));
        const unsigned int vw[4] = {vv.x, vv.y, vv.z, vv.w};
#pragma unroll
        for (int k = 0; k < 4; ++k) {
          o[2 * k] += p[g] * bflo(vw[k]);
          o[2 * k + 1] += p[g] * bfhi(vw[k]);
        }
      }
      uint4 w;
      w.x = (unsigned int)f2bf(o[0]) | ((unsigned int)f2bf(o[1]) << 16);
      w.y = (unsigned int)f2bf(o[2]) | ((unsigned int)f2bf(o[3]) << 16);
      w.z = (unsigned int)f2bf(o[4]) | ((unsigned int)f2bf(o[5]) << 16);
      w.w = (unsigned int)f2bf(o[6]) | ((unsigned int)f2bf(o[7]) << 16);
      *(uint4*)(qpark + swz(h * 128 + c * 16)) = w;
    }
  }
  __syncthreads();

  uint4* dst = (uint4*)(ctx + (size_t)blk * (T_BLK * 768));
#pragma unroll
  for (int it = 0; it < 6; ++it) {
    const int l = it * 128 + tid;
    const int tok2 = l / 96;
    const int boff = (l - tok2 * 96) * 16;
    dst[l] = *(const uint4*)(lds + tok2 * ROWB + swz(boff));
  }
}

extern "C" void kernel_launch(void* const* d_in, const int* in_sizes, int n_in,
                              void* d_out, int out_size, void* d_ws, size_t ws_size,
                              hipStream_t stream) {
  const float* x = (const float*)d_in[0];
  const float* Wq = (const float*)d_in[1];
  const float* bq = (const float*)d_in[2];
  const float* Wk = (const float*)d_in[3];
  const float* bk = (const float*)d_in[4];
  const float* Wv = (const float*)d_in[5];
  const float* bv = (const float*)d_in[6];
  const float* Wo = (const float*)d_in[7];
  const float* bo = (const float*)d_in[8];
  float* out = (float*)d_out;

  char* ws = (char*)d_ws;
  unsigned short* x_bf = (unsigned short*)ws;
  unsigned short* ctx = (unsigned short*)ws;  // alias: x_bf dead before attn
  unsigned short* qkv = (unsigned short*)(ws + 100663296u);
  unsigned short* wqkv = (unsigned short*)(ws + 402653184u);
  unsigned short* wo_bf = (unsigned short*)(ws + 406192128u);
  float* bqkv = (float*)(ws + 407371776u);

  cvt_all_kernel<<<51459, 256, 0, stream>>>(x, Wq, Wk, Wv, Wo, bq, bk, bv,
                                            x_bf, wqkv, wo_bf, bqkv);

  gemm256<0><<<(N_TOK / 256) * (2304 / 256), 1024, 0, stream>>>(
      x_bf, wqkv, bqkv, qkv, HIDDEN, 2304 / 256, 2304);

  attn_kernel<<<N_TOK / T_BLK, 128, 0, stream>>>(qkv, ctx);

  gemm256<1><<<(N_TOK / 256) * (HIDDEN / 256), 1024, 0, stream>>>(
      ctx, wo_bf, bo, out, HIDDEN, HIDDEN / 256, HIDDEN);
}